// Round 3
// baseline (339.821 us; speedup 1.0000x reference)
//
#include <hip/hip_runtime.h>
#include <stdint.h>
#include <math.h>

#define B_ 256
#define H_ 128
#define S_ 2048

typedef __attribute__((ext_vector_type(8))) short short8;
typedef __attribute__((ext_vector_type(4))) float f32x4;

typedef const __attribute__((address_space(1))) void gvoid_t;
typedef __attribute__((address_space(3))) void lvoid_t;

// ---------- helpers ----------
__device__ __forceinline__ unsigned short f2bf(float f) {
  uint32_t u = __builtin_bit_cast(uint32_t, f);
  u += 0x7fffu + ((u >> 16) & 1u);          // round-to-nearest-even
  return (unsigned short)(u >> 16);
}

__device__ __forceinline__ float tanh_fast(float x) {
  float ax = fabsf(x);
  float e = __expf(-2.0f * ax);
  float t = (1.0f - e) / (1.0f + e);
  return copysignf(t, x);
}

// ---------- ws layout (bytes) ----------
// wsA frags : [0, 98304)          24 tiles x 4 ksteps x 64 lanes x 8 bf16
// flag      : [114688, 114692)
// c1        : [131072, 262144)    [B,H] f32
// c2        : [262144, 393216)    [B,H] f32
// ctx       : [393216, 524288)    [B,H] f32
// attns     : [524288, 2621440)   [B,S] f32
// score     : [2621440, 4718592)  [B,S] f32
// wsT       : [8388608, 8388608+134217728)  [B][S][H] bf16 transposed static
#define WS_NEED 4718592u
#define WST_OFF 8388608u
#define WS_T_NEED (WST_OFF + (size_t)B_ * S_ * H_ * 2)

// Pre-swizzle A-operand fragments (bf16) for mfma_f32_16x16x32_bf16.
// tiles 0..7  : W_a rows 0..127   (stage 1, static operand)
// tiles 8..15 : W2_a rows 0..127  (stage 2)
// tiles 16..23: W_b rows 0..127   (stage 1, dynamic operand)
__global__ __launch_bounds__(256) void prep_wfrags(
    const float* __restrict__ W, const float* __restrict__ W2,
    unsigned short* __restrict__ wsA) {
  int idx = blockIdx.x * 256 + threadIdx.x;   // 24*4*64*8 = 49152 total
  if (idx >= 24 * 4 * 64 * 8) return;
  int j = idx & 7;
  int lane = (idx >> 3) & 63;
  int t = (idx >> 9) & 3;
  int tile = idx >> 11;
  int li = lane & 15;
  int k = t * 32 + (lane >> 4) * 8 + j;
  float val;
  if (tile < 8)        val = W[(tile * 16 + li) * 384 + k];             // W_a
  else if (tile < 16)  val = W2[((tile - 8) * 16 + li) * 256 + k];      // W2_a
  else                 val = W[((tile - 16) * 16 + li) * 384 + 128 + k];// W_b
  wsA[idx] = f2bf(val);
}

// c1[b,h] = sum_k W[h, 256+k] * dec[b,k]
__global__ __launch_bounds__(128) void prep_c1(
    const float* __restrict__ W, const float* __restrict__ dec,
    float* __restrict__ c1) {
  int b = blockIdx.x;
  int h = threadIdx.x;
  __shared__ float sdec[H_];
  sdec[h] = dec[b * H_ + h];
  __syncthreads();
  const float* wr = W + h * 384 + 256;
  float acc = 0.f;
  #pragma unroll 4
  for (int k = 0; k < 128; ++k) acc += wr[k] * sdec[k];
  c1[b * H_ + h] = acc;
}

// Detect mask element width: 0 = int32, 1 = uint8(bool), 2 = float32.
__global__ void detect_mask(const unsigned char* __restrict__ mb, int* __restrict__ flag) {
  __shared__ int sGT1, sNZ;
  if (threadIdx.x == 0) { sGT1 = 0; sNZ = 0; }
  __syncthreads();
  int gt1 = 0, nz = 0;
  for (int i = threadIdx.x; i < 8192; i += 256) {
    unsigned char c = mb[i];
    if (c > 1) gt1 = 1;
    if ((i & 3) && c) nz = 1;
  }
  if (gt1) atomicOr(&sGT1, 1);
  if (nz)  atomicOr(&sNZ, 1);
  __syncthreads();
  if (threadIdx.x == 0) *flag = sGT1 ? 2 : (sNZ ? 1 : 0);
}

// Stage 1. grid (32, B). Block: s-chunk of 64, 4 waves; wave w owns s-cols [16w,16w+16).
// LDS: static [128k][64s] f32 (gl_lds, src col ^ 8*((k>>3)&3)),
//      dyn    [64s][128k] f32 (gl_lds, src 16B-chunk ^ (s&7)).
// Optionally stores transposed bf16 static copy to wsT.
__global__ __launch_bounds__(256) void stage1(
    const float* __restrict__ sEmb, const float* __restrict__ dEmb,
    const unsigned short* __restrict__ wsA, const float* __restrict__ c1,
    const float* __restrict__ v, float* __restrict__ attns,
    unsigned short* __restrict__ wsT) {
  int b = blockIdx.y;
  int tid = threadIdx.x;
  int lane = tid & 63, w = tid >> 6, g = lane >> 4, li = lane & 15;
  __shared__ float sS[128 * 64];
  __shared__ float sD[64 * 128];
  __shared__ float sc1[H_], sv[H_];

  const int schunk = blockIdx.x * 64;
  const size_t sbase = (size_t)b * H_ * S_;
  const size_t dbase = (size_t)b * S_ * H_;

  // static -> LDS: 8 instrs/wave, 4 rows each (256B/row)
  {
    int lrow = lane >> 4, lcol4 = 4 * (lane & 15);
    #pragma unroll
    for (int i = 0; i < 8; ++i) {
      int r = 32 * w + 4 * i + lrow;
      int gcol = lcol4 ^ (((r >> 3) & 3) << 3);
      const float* src = sEmb + sbase + (size_t)r * S_ + schunk + gcol;
      __builtin_amdgcn_global_load_lds((gvoid_t*)src,
                                       (lvoid_t*)&sS[(32 * w + 4 * i) * 64],
                                       16, 0, 0);
    }
  }
  // dyn -> LDS: 8 instrs/wave, 2 rows each (512B/row), contiguous source rows
  {
    int lrow = lane >> 5, lch = lane & 31;
    #pragma unroll
    for (int i = 0; i < 8; ++i) {
      int s = 16 * w + 2 * i + lrow;
      int sch = lch ^ (s & 7);
      const float* src = dEmb + dbase + (size_t)(schunk + s) * H_ + 4 * sch;
      __builtin_amdgcn_global_load_lds((gvoid_t*)src,
                                       (lvoid_t*)&sD[(16 * w + 2 * i) * 128],
                                       16, 0, 0);
    }
  }

  if (tid < 128) { sc1[tid] = c1[b * H_ + tid]; sv[tid] = v[tid]; }
  __syncthreads();

  f32x4 acc[8];
  #pragma unroll
  for (int m = 0; m < 8; ++m) acc[m] = (f32x4)0.0f;

  const int srow = 16 * w + li;
  const int colA = srow ^ (g << 3);

  #pragma unroll
  for (int t = 0; t < 4; ++t) {
    // static fragment (scalar b32 reads, 2-way banked) + cvt
    short8 bS;
    #pragma unroll
    for (int j = 0; j < 8; ++j)
      bS[j] = (short)f2bf(sS[(32 * t + 8 * g + j) * 64 + colA]);
    // dyn fragment (2 x b128, 2-way banked) + cvt
    f32x4 d0 = *(const f32x4*)&sD[srow * 128 + 4 * ((8 * t + 2 * g + 0) ^ (li & 7))];
    f32x4 d1 = *(const f32x4*)&sD[srow * 128 + 4 * ((8 * t + 2 * g + 1) ^ (li & 7))];
    short8 bD;
    bD[0] = (short)f2bf(d0.x); bD[1] = (short)f2bf(d0.y);
    bD[2] = (short)f2bf(d0.z); bD[3] = (short)f2bf(d0.w);
    bD[4] = (short)f2bf(d1.x); bD[5] = (short)f2bf(d1.y);
    bD[6] = (short)f2bf(d1.z); bD[7] = (short)f2bf(d1.w);

    if (wsT) {
      *(short8*)&wsT[((size_t)b * S_ + schunk + srow) * H_ + 32 * t + 8 * g] = bS;
    }

    #pragma unroll
    for (int m = 0; m < 8; ++m) {
      short8 aW = *(const short8*)(wsA + (size_t)((m * 4 + t) * 64 + lane) * 8);
      short8 aB = *(const short8*)(wsA + (size_t)(((16 + m) * 4 + t) * 64 + lane) * 8);
      acc[m] = __builtin_amdgcn_mfma_f32_16x16x32_bf16(aW, bS, acc[m], 0, 0, 0);
      acc[m] = __builtin_amdgcn_mfma_f32_16x16x32_bf16(aB, bD, acc[m], 0, 0, 0);
    }
  }

  float part = 0.f;
  #pragma unroll
  for (int m = 0; m < 8; ++m)
    #pragma unroll
    for (int r = 0; r < 4; ++r) {
      int h = m * 16 + g * 4 + r;
      part += sv[h] * tanh_fast(acc[m][r] + sc1[h]);
    }
  part += __shfl_xor(part, 16);
  part += __shfl_xor(part, 32);
  if (lane < 16) attns[(size_t)b * S_ + schunk + 16 * w + lane] = part;
}

// Softmax(attns row) + context. grid (4, B): 4 h-quarters per batch.
__global__ __launch_bounds__(256) void kmid_a(
    const float* __restrict__ attns, const float* __restrict__ sEmb,
    float* __restrict__ ctx) {
  int q = blockIdx.x, b = blockIdx.y;
  int tid = threadIdx.x, lane = tid & 63, w = tid >> 6;
  __shared__ float p[S_];
  __shared__ float wred[4];
  __shared__ float sred;

  float a[8];
  #pragma unroll
  for (int i = 0; i < 8; ++i) a[i] = attns[(size_t)b * S_ + i * 256 + tid];
  float mx = a[0];
  #pragma unroll
  for (int i = 1; i < 8; ++i) mx = fmaxf(mx, a[i]);
  #pragma unroll
  for (int off = 32; off >= 1; off >>= 1) mx = fmaxf(mx, __shfl_xor(mx, off));
  if (lane == 0) wred[w] = mx;
  __syncthreads();
  if (tid == 0) sred = fmaxf(fmaxf(wred[0], wred[1]), fmaxf(wred[2], wred[3]));
  __syncthreads();
  mx = sred;
  __syncthreads();
  float sum = 0.f;
  #pragma unroll
  for (int i = 0; i < 8; ++i) {
    float e = __expf(a[i] - mx);
    p[i * 256 + tid] = e;
    sum += e;
  }
  #pragma unroll
  for (int off = 32; off >= 1; off >>= 1) sum += __shfl_xor(sum, off);
  if (lane == 0) wred[w] = sum;
  __syncthreads();
  if (tid == 0) sred = 1.0f / (wred[0] + wred[1] + wred[2] + wred[3]);
  __syncthreads();
  float inv = sred;

  #pragma unroll
  for (int hh = 0; hh < 8; ++hh) {
    int h = q * 32 + w * 8 + hh;
    const f32x4* xp = (const f32x4*)(sEmb + (size_t)b * H_ * S_ + (size_t)h * S_);
    float av = 0.f;
    #pragma unroll
    for (int it = 0; it < 8; ++it) {
      f32x4 x = xp[it * 64 + lane];
      f32x4 pp = *(const f32x4*)&p[(it * 64 + lane) * 4];
      av += x.x * pp.x + x.y * pp.y + x.z * pp.z + x.w * pp.w;
    }
    #pragma unroll
    for (int off = 32; off >= 1; off >>= 1) av += __shfl_xor(av, off);
    if (lane == 0) ctx[b * H_ + h] = av * inv;
  }
}

// c2[b,h] = sum_k W2[h, 128+k] * ctx[b,k]
__global__ __launch_bounds__(128) void kmid_b(
    const float* __restrict__ W2, const float* __restrict__ ctx,
    float* __restrict__ c2) {
  int b = blockIdx.x;
  int h = threadIdx.x;
  __shared__ float sc[H_];
  sc[h] = ctx[b * H_ + h];
  __syncthreads();
  const float* wr = W2 + h * 256 + 128;
  float acc = 0.f;
  #pragma unroll 4
  for (int k = 0; k < 128; ++k) acc += wr[k] * sc[k];
  c2[b * H_ + h] = acc;
}

__device__ __forceinline__ void stage2_epilogue(
    int b, int lane, int g, const f32x4* acc2, const float* sc2, const float* sv2,
    const unsigned char* mask8, int f, int s0, float* score) {
  float part = 0.f;
  #pragma unroll
  for (int m = 0; m < 8; ++m)
    #pragma unroll
    for (int r = 0; r < 4; ++r) {
      int h = m * 16 + g * 4 + r;
      part += sv2[h] * tanh_fast(acc2[m][r] + sc2[h]);
    }
  part += __shfl_xor(part, 16);
  part += __shfl_xor(part, 32);
  if (lane < 16) {
    size_t mi = (size_t)b * S_ + s0 + lane;
    bool msk;
    if (f == 1)      msk = mask8[mi] != 0;
    else if (f == 2) msk = ((const float*)mask8)[mi] != 0.0f;
    else             msk = ((const int*)mask8)[mi] != 0;
    score[mi] = msk ? -INFINITY : part;
  }
}

// Stage 2 (bf16 transposed copy path). grid (16, B), s-chunk 128, 4 waves, 2 s16-tiles/wave.
__global__ __launch_bounds__(256) void stage2T(
    const unsigned short* __restrict__ wsT, const unsigned short* __restrict__ wsA,
    const float* __restrict__ c2, const float* __restrict__ v2,
    const unsigned char* __restrict__ mask8, const int* __restrict__ flag,
    float* __restrict__ score) {
  int b = blockIdx.y;
  int tid = threadIdx.x;
  int lane = tid & 63, w = tid >> 6, g = lane >> 4, li = lane & 15;
  __shared__ unsigned short sT[128 * 128];   // [s][k] bf16, 16B-chunk ^ (s&7)
  __shared__ float sc2[H_], sv2[H_];

  const int schunk = blockIdx.x * 128;

  {
    int lrow = lane >> 4, lch = lane & 15;
    #pragma unroll
    for (int i = 0; i < 8; ++i) {
      int r = 32 * w + 4 * i + lrow;
      int sch = lch ^ (r & 7);
      const unsigned short* src = wsT + ((size_t)b * S_ + schunk + r) * H_ + 8 * sch;
      __builtin_amdgcn_global_load_lds((gvoid_t*)src,
                                       (lvoid_t*)&sT[(32 * w + 4 * i) * 128],
                                       16, 0, 0);
    }
  }

  if (tid < 128) { sc2[tid] = c2[b * H_ + tid]; sv2[tid] = v2[tid]; }
  __syncthreads();

  f32x4 acc[2][8];
  #pragma unroll
  for (int tt = 0; tt < 2; ++tt)
    #pragma unroll
    for (int m = 0; m < 8; ++m) acc[tt][m] = (f32x4)0.0f;

  #pragma unroll
  for (int t = 0; t < 4; ++t) {
    short8 bS[2];
    #pragma unroll
    for (int tt = 0; tt < 2; ++tt) {
      int r = 32 * w + 16 * tt + li;
      bS[tt] = *(const short8*)&sT[r * 128 + 8 * ((4 * t + g) ^ (li & 7))];
    }
    #pragma unroll
    for (int m = 0; m < 8; ++m) {
      short8 aW = *(const short8*)(wsA + (size_t)(((8 + m) * 4 + t) * 64 + lane) * 8);
      acc[0][m] = __builtin_amdgcn_mfma_f32_16x16x32_bf16(aW, bS[0], acc[0][m], 0, 0, 0);
      acc[1][m] = __builtin_amdgcn_mfma_f32_16x16x32_bf16(aW, bS[1], acc[1][m], 0, 0, 0);
    }
  }

  int f = *flag;
  stage2_epilogue(b, lane, g, acc[0], sc2, sv2, mask8, f, schunk + 32 * w, score);
  stage2_epilogue(b, lane, g, acc[1], sc2, sv2, mask8, f, schunk + 32 * w + 16, score);
}

// Stage 2 fallback (f32 path, no wsT). grid (32, B), s-chunk 64 like stage1.
__global__ __launch_bounds__(256) void stage2F(
    const float* __restrict__ sEmb, const unsigned short* __restrict__ wsA,
    const float* __restrict__ c2, const float* __restrict__ v2,
    const unsigned char* __restrict__ mask8, const int* __restrict__ flag,
    float* __restrict__ score) {
  int b = blockIdx.y;
  int tid = threadIdx.x;
  int lane = tid & 63, w = tid >> 6, g = lane >> 4, li = lane & 15;
  __shared__ float sS[128 * 64];
  __shared__ float sc2[H_], sv2[H_];

  const int schunk = blockIdx.x * 64;
  const size_t sbase = (size_t)b * H_ * S_;

  {
    int lrow = lane >> 4, lcol4 = 4 * (lane & 15);
    #pragma unroll
    for (int i = 0; i < 8; ++i) {
      int r = 32 * w + 4 * i + lrow;
      int gcol = lcol4 ^ (((r >> 3) & 3) << 3);
      const float* src = sEmb + sbase + (size_t)r * S_ + schunk + gcol;
      __builtin_amdgcn_global_load_lds((gvoid_t*)src,
                                       (lvoid_t*)&sS[(32 * w + 4 * i) * 64],
                                       16, 0, 0);
    }
  }

  if (tid < 128) { sc2[tid] = c2[b * H_ + tid]; sv2[tid] = v2[tid]; }
  __syncthreads();

  f32x4 acc[8];
  #pragma unroll
  for (int m = 0; m < 8; ++m) acc[m] = (f32x4)0.0f;

  const int colA = (16 * w + li) ^ (g << 3);
  #pragma unroll
  for (int t = 0; t < 4; ++t) {
    short8 bS;
    #pragma unroll
    for (int j = 0; j < 8; ++j)
      bS[j] = (short)f2bf(sS[(32 * t + 8 * g + j) * 64 + colA]);
    #pragma unroll
    for (int m = 0; m < 8; ++m) {
      short8 aW = *(const short8*)(wsA + (size_t)(((8 + m) * 4 + t) * 64 + lane) * 8);
      acc[m] = __builtin_amdgcn_mfma_f32_16x16x32_bf16(aW, bS, acc[m], 0, 0, 0);
    }
  }

  int f = *flag;
  stage2_epilogue(b, lane, g, acc, sc2, sv2, mask8, f, schunk + 16 * w, score);
}

// Final row softmax -> out
__global__ __launch_bounds__(256) void ksoftmax(
    const float* __restrict__ score, float* __restrict__ out) {
  int b = blockIdx.x;
  int tid = threadIdx.x, lane = tid & 63, w = tid >> 6;
  __shared__ float wred[4];
  __shared__ float sred;
  float a[8];
  #pragma unroll
  for (int i = 0; i < 8; ++i) a[i] = score[(size_t)b * S_ + i * 256 + tid];
  float mx = a[0];
  #pragma unroll
  for (int i = 1; i < 8; ++i) mx = fmaxf(mx, a[i]);
  #pragma unroll
  for (int off = 32; off >= 1; off >>= 1) mx = fmaxf(mx, __shfl_xor(mx, off));
  if (lane == 0) wred[w] = mx;
  __syncthreads();
  if (tid == 0) sred = fmaxf(fmaxf(wred[0], wred[1]), fmaxf(wred[2], wred[3]));
  __syncthreads();
  mx = sred;
  __syncthreads();
  float e[8];
  float sum = 0.f;
  #pragma unroll
  for (int i = 0; i < 8; ++i) { e[i] = __expf(a[i] - mx); sum += e[i]; }
  #pragma unroll
  for (int off = 32; off >= 1; off >>= 1) sum += __shfl_xor(sum, off);
  if (lane == 0) wred[w] = sum;
  __syncthreads();
  if (tid == 0) sred = 1.0f / (wred[0] + wred[1] + wred[2] + wred[3]);
  __syncthreads();
  float inv = sred;
  #pragma unroll
  for (int i = 0; i < 8; ++i) out[(size_t)b * S_ + i * 256 + tid] = e[i] * inv;
}

extern "C" void kernel_launch(void* const* d_in, const int* in_sizes, int n_in,
                              void* d_out, int out_size, void* d_ws, size_t ws_size,
                              hipStream_t stream) {
  (void)in_sizes; (void)n_in; (void)out_size;
  if (ws_size < WS_NEED) return;
  const float* sEmb = (const float*)d_in[0];
  const float* dEmb = (const float*)d_in[1];
  const float* dec  = (const float*)d_in[2];
  const unsigned char* mask = (const unsigned char*)d_in[3];
  const float* v    = (const float*)d_in[4];
  const float* W    = (const float*)d_in[5];
  const float* v2   = (const float*)d_in[6];
  const float* W2   = (const float*)d_in[7];

  char* ws = (char*)d_ws;
  unsigned short* wsA = (unsigned short*)(ws);
  int*   flag  = (int*)  (ws + 114688);
  float* c1    = (float*)(ws + 131072);
  float* c2    = (float*)(ws + 262144);
  float* ctx   = (float*)(ws + 393216);
  float* attns = (float*)(ws + 524288);
  float* score = (float*)(ws + 2621440);
  bool useT = (ws_size >= WS_T_NEED);
  unsigned short* wsT = useT ? (unsigned short*)(ws + WST_OFF) : nullptr;

  prep_wfrags<<<192, 256, 0, stream>>>(W, W2, wsA);
  prep_c1<<<B_, 128, 0, stream>>>(W, dec, c1);
  detect_mask<<<1, 256, 0, stream>>>(mask, flag);
  stage1<<<dim3(32, B_), 256, 0, stream>>>(sEmb, dEmb, wsA, c1, v, attns, wsT);
  kmid_a<<<dim3(4, B_), 256, 0, stream>>>(attns, sEmb, ctx);
  kmid_b<<<B_, 128, 0, stream>>>(W2, ctx, c2);
  if (useT)
    stage2T<<<dim3(16, B_), 256, 0, stream>>>(wsT, wsA, c2, v2, mask, flag, score);
  else
    stage2F<<<dim3(32, B_), 256, 0, stream>>>(sEmb, wsA, c2, v2, mask, flag, score);
  ksoftmax<<<B_, 256, 0, stream>>>(score, (float*)d_out);
}

// Round 4
// 286.484 us; speedup vs baseline: 1.1862x; 1.1862x over previous
//
#include <hip/hip_runtime.h>
#include <stdint.h>
#include <math.h>

#define B_ 256
#define H_ 128
#define S_ 2048

typedef __attribute__((ext_vector_type(8))) short short8;
typedef __attribute__((ext_vector_type(4))) float f32x4;

typedef const __attribute__((address_space(1))) void gvoid_t;
typedef __attribute__((address_space(3))) void lvoid_t;

// ---------- helpers ----------
__device__ __forceinline__ unsigned short f2bf(float f) {
  uint32_t u = __builtin_bit_cast(uint32_t, f);
  u += 0x7fffu + ((u >> 16) & 1u);          // round-to-nearest-even
  return (unsigned short)(u >> 16);
}

__device__ __forceinline__ float tanh_fast(float x) {
  float ax = fabsf(x);
  float e = __expf(-2.0f * ax);
  float t = (1.0f - e) / (1.0f + e);
  return copysignf(t, x);
}

// ---------- ws layout (bytes) ----------
// wsA frags : [0, 98304)          24 tiles x 4 ksteps x 64 lanes x 8 bf16
// flag      : [114688, 114692)
// c1        : [131072, 262144)    [B,H] f32
// c2        : [262144, 393216)    [B,H] f32
// ctx       : [393216, 524288)    [B,H] f32
// attns     : [524288, 2621440)   [B,S] f32
// score     : [2621440, 4718592)  [B,S] f32
// wsT       : [8388608, +134217728)  bf16 static in MFMA B-frag layout:
//             [b][stile(S/16)][t(4)][lane(64)][8]
#define WS_NEED 4718592u
#define WST_OFF 8388608u
#define WS_T_NEED (WST_OFF + (size_t)B_ * (S_/16) * 4 * 64 * 8 * 2)

// Pre-swizzle A-operand fragments (bf16) for mfma_f32_16x16x32_bf16.
// tiles 0..7  : W_a rows 0..127   (stage 1, static operand)
// tiles 8..15 : W2_a rows 0..127  (stage 2)
// tiles 16..23: W_b rows 0..127   (stage 1, dynamic operand)
__global__ __launch_bounds__(256) void prep_wfrags(
    const float* __restrict__ W, const float* __restrict__ W2,
    unsigned short* __restrict__ wsA) {
  int idx = blockIdx.x * 256 + threadIdx.x;   // 24*4*64*8 = 49152 total
  if (idx >= 24 * 4 * 64 * 8) return;
  int j = idx & 7;
  int lane = (idx >> 3) & 63;
  int t = (idx >> 9) & 3;
  int tile = idx >> 11;
  int li = lane & 15;
  int k = t * 32 + (lane >> 4) * 8 + j;
  float val;
  if (tile < 8)        val = W[(tile * 16 + li) * 384 + k];             // W_a
  else if (tile < 16)  val = W2[((tile - 8) * 16 + li) * 256 + k];      // W2_a
  else                 val = W[((tile - 16) * 16 + li) * 384 + 128 + k];// W_b
  wsA[idx] = f2bf(val);
}

// c1[b,h] = sum_k W[h, 256+k] * dec[b,k]
__global__ __launch_bounds__(128) void prep_c1(
    const float* __restrict__ W, const float* __restrict__ dec,
    float* __restrict__ c1) {
  int b = blockIdx.x;
  int h = threadIdx.x;
  __shared__ float sdec[H_];
  sdec[h] = dec[b * H_ + h];
  __syncthreads();
  const float* wr = W + h * 384 + 256;
  float acc = 0.f;
  #pragma unroll 4
  for (int k = 0; k < 128; ++k) acc += wr[k] * sdec[k];
  c1[b * H_ + h] = acc;
}

// Detect mask element width: 0 = int32, 1 = uint8(bool), 2 = float32.
__global__ void detect_mask(const unsigned char* __restrict__ mb, int* __restrict__ flag) {
  __shared__ int sGT1, sNZ;
  if (threadIdx.x == 0) { sGT1 = 0; sNZ = 0; }
  __syncthreads();
  int gt1 = 0, nz = 0;
  for (int i = threadIdx.x; i < 8192; i += 256) {
    unsigned char c = mb[i];
    if (c > 1) gt1 = 1;
    if ((i & 3) && c) nz = 1;
  }
  if (gt1) atomicOr(&sGT1, 1);
  if (nz)  atomicOr(&sNZ, 1);
  __syncthreads();
  if (threadIdx.x == 0) *flag = sGT1 ? 2 : (sNZ ? 1 : 0);
}

// Stage 1, W-in-registers. grid (4, B): each block owns 512 s (8 chunks of 64).
// Wave w owns h m-tiles {2w, 2w+1}; W_a/W_b frags live in 64 VGPRs, loaded ONCE.
// Per chunk: wave w converts s-tile w f32->bf16 frag-layout into LDS (shared by
// all waves) + streams the static frags to wsT; MFMA phase overlaps next fetch.
__global__ __launch_bounds__(256) void stage1(
    const float* __restrict__ sEmb, const float* __restrict__ dEmb,
    const unsigned short* __restrict__ wsA, const float* __restrict__ c1,
    const float* __restrict__ v, float* __restrict__ attns,
    unsigned short* __restrict__ wsT) {
  const int b = blockIdx.y;
  const int tid = threadIdx.x;
  const int lane = tid & 63, w = tid >> 6, g = lane >> 4, li = lane & 15;
  __shared__ float sS[128 * 64];            // [k][s] f32, stored col = s ^ (((k>>3)&3)<<3)
  __shared__ float sD[64 * 128];            // [s][k] f32, stored 16B-chunk = ch ^ (s&7)
  __shared__ unsigned short frag[4][8][512];// [stile][t | 4+t][lane*8] bf16
  __shared__ float spart[256];
  __shared__ float sc1[H_], sv[H_];

  const size_t sbase = (size_t)b * H_ * S_;
  const size_t dbase = (size_t)b * S_ * H_;
  const int sblk = blockIdx.x * 512;

  // ---- W fragments -> registers (once) ----
  short8 aW[2][4], aB[2][4];
  #pragma unroll
  for (int mm = 0; mm < 2; ++mm)
    #pragma unroll
    for (int t = 0; t < 4; ++t) {
      aW[mm][t] = *(const short8*)(wsA + (size_t)(((2 * w + mm) * 4 + t) * 64 + lane) * 8);
      aB[mm][t] = *(const short8*)(wsA + (size_t)(((16 + 2 * w + mm) * 4 + t) * 64 + lane) * 8);
    }

  if (tid < 128) { sc1[tid] = c1[b * H_ + tid]; sv[tid] = v[tid]; }

  auto stage = [&](int soff) {
    int lrow = lane >> 4, lcol4 = 4 * (lane & 15);
    #pragma unroll
    for (int i = 0; i < 8; ++i) {
      int r = 32 * w + 4 * i + lrow;
      int gcol = lcol4 ^ (((r >> 3) & 3) << 3);
      const float* src = sEmb + sbase + (size_t)r * S_ + soff + gcol;
      __builtin_amdgcn_global_load_lds((gvoid_t*)src, (lvoid_t*)&sS[(32 * w + 4 * i) * 64],
                                       16, 0, 0);
    }
    int lrow2 = lane >> 5, lch = lane & 31;
    #pragma unroll
    for (int i = 0; i < 8; ++i) {
      int s = 16 * w + 2 * i + lrow2;
      int sch = lch ^ (s & 7);
      const float* src = dEmb + dbase + (size_t)(soff + s) * H_ + 4 * sch;
      __builtin_amdgcn_global_load_lds((gvoid_t*)src, (lvoid_t*)&sD[(16 * w + 2 * i) * 128],
                                       16, 0, 0);
    }
  };
  stage(sblk);

  const int colA = (16 * w + li) ^ (g << 3);  // swizzled stored col for static reads
  const int srow = 16 * w + li;               // dyn row / frag s-col

  for (int c = 0; c < 8; ++c) {
    const int soff = sblk + c * 64;
    __syncthreads();                          // A: chunk data landed, frag free
    // ---- convert phase: wave w builds s-tile w's B-frags ----
    #pragma unroll
    for (int t = 0; t < 4; ++t) {
      short8 bS;
      #pragma unroll
      for (int j = 0; j < 8; ++j)
        bS[j] = (short)f2bf(sS[(32 * t + 8 * g + j) * 64 + colA]);
      f32x4 d0 = *(const f32x4*)&sD[srow * 128 + 4 * ((8 * t + 2 * g + 0) ^ (li & 7))];
      f32x4 d1 = *(const f32x4*)&sD[srow * 128 + 4 * ((8 * t + 2 * g + 1) ^ (li & 7))];
      short8 bD;
      bD[0] = (short)f2bf(d0.x); bD[1] = (short)f2bf(d0.y);
      bD[2] = (short)f2bf(d0.z); bD[3] = (short)f2bf(d0.w);
      bD[4] = (short)f2bf(d1.x); bD[5] = (short)f2bf(d1.y);
      bD[6] = (short)f2bf(d1.z); bD[7] = (short)f2bf(d1.w);
      *(short8*)&frag[w][t][lane * 8] = bS;
      *(short8*)&frag[w][4 + t][lane * 8] = bD;
      if (wsT)
        *(short8*)&wsT[(((size_t)b * (S_ / 16) + (soff >> 4) + w) * 4 + t) * 512 + lane * 8] = bS;
    }
    __syncthreads();                          // B: frags visible, sS/sD dead
    if (c + 1 < 8) stage(soff + 64);          // prefetch overlaps MFMA phase

    // ---- MFMA phase ----
    f32x4 acc[4][2];
    #pragma unroll
    for (int st = 0; st < 4; ++st) { acc[st][0] = (f32x4)0.0f; acc[st][1] = (f32x4)0.0f; }
    #pragma unroll
    for (int st = 0; st < 4; ++st)
      #pragma unroll
      for (int t = 0; t < 4; ++t) {
        short8 bS = *(const short8*)&frag[st][t][lane * 8];
        short8 bD = *(const short8*)&frag[st][4 + t][lane * 8];
        acc[st][0] = __builtin_amdgcn_mfma_f32_16x16x32_bf16(aW[0][t], bS, acc[st][0], 0, 0, 0);
        acc[st][1] = __builtin_amdgcn_mfma_f32_16x16x32_bf16(aW[1][t], bS, acc[st][1], 0, 0, 0);
        acc[st][0] = __builtin_amdgcn_mfma_f32_16x16x32_bf16(aB[0][t], bD, acc[st][0], 0, 0, 0);
        acc[st][1] = __builtin_amdgcn_mfma_f32_16x16x32_bf16(aB[1][t], bD, acc[st][1], 0, 0, 0);
      }

    // ---- epilogue: partial v-dot over this wave's 32 h ----
    #pragma unroll
    for (int st = 0; st < 4; ++st) {
      float part = 0.f;
      #pragma unroll
      for (int mm = 0; mm < 2; ++mm)
        #pragma unroll
        for (int r = 0; r < 4; ++r) {
          int h = 32 * w + 16 * mm + 4 * g + r;
          part += sv[h] * tanh_fast(acc[st][mm][r] + sc1[h]);
        }
      part += __shfl_xor(part, 16);
      part += __shfl_xor(part, 32);
      if (lane < 16) spart[w * 64 + st * 16 + li] = part;
    }
    __syncthreads();                          // C: partials visible
    if (tid < 64)
      attns[(size_t)b * S_ + soff + tid] =
          spart[tid] + spart[64 + tid] + spart[128 + tid] + spart[192 + tid];
  }
}

// Softmax(attns row) + context. grid (4, B): 4 h-quarters per batch.
__global__ __launch_bounds__(256) void kmid_a(
    const float* __restrict__ attns, const float* __restrict__ sEmb,
    float* __restrict__ ctx) {
  int q = blockIdx.x, b = blockIdx.y;
  int tid = threadIdx.x, lane = tid & 63, w = tid >> 6;
  __shared__ float p[S_];
  __shared__ float wred[4];
  __shared__ float sred;

  float a[8];
  #pragma unroll
  for (int i = 0; i < 8; ++i) a[i] = attns[(size_t)b * S_ + i * 256 + tid];
  float mx = a[0];
  #pragma unroll
  for (int i = 1; i < 8; ++i) mx = fmaxf(mx, a[i]);
  #pragma unroll
  for (int off = 32; off >= 1; off >>= 1) mx = fmaxf(mx, __shfl_xor(mx, off));
  if (lane == 0) wred[w] = mx;
  __syncthreads();
  if (tid == 0) sred = fmaxf(fmaxf(wred[0], wred[1]), fmaxf(wred[2], wred[3]));
  __syncthreads();
  mx = sred;
  __syncthreads();
  float sum = 0.f;
  #pragma unroll
  for (int i = 0; i < 8; ++i) {
    float e = __expf(a[i] - mx);
    p[i * 256 + tid] = e;
    sum += e;
  }
  #pragma unroll
  for (int off = 32; off >= 1; off >>= 1) sum += __shfl_xor(sum, off);
  if (lane == 0) wred[w] = sum;
  __syncthreads();
  if (tid == 0) sred = 1.0f / (wred[0] + wred[1] + wred[2] + wred[3]);
  __syncthreads();
  float inv = sred;

  #pragma unroll
  for (int hh = 0; hh < 8; ++hh) {
    int h = q * 32 + w * 8 + hh;
    const f32x4* xp = (const f32x4*)(sEmb + (size_t)b * H_ * S_ + (size_t)h * S_);
    float av = 0.f;
    #pragma unroll
    for (int it = 0; it < 8; ++it) {
      f32x4 x = xp[it * 64 + lane];
      f32x4 pp = *(const f32x4*)&p[(it * 64 + lane) * 4];
      av += x.x * pp.x + x.y * pp.y + x.z * pp.z + x.w * pp.w;
    }
    #pragma unroll
    for (int off = 32; off >= 1; off >>= 1) av += __shfl_xor(av, off);
    if (lane == 0) ctx[b * H_ + h] = av * inv;
  }
}

// c2[b,h] = sum_k W2[h, 128+k] * ctx[b,k]
__global__ __launch_bounds__(128) void kmid_b(
    const float* __restrict__ W2, const float* __restrict__ ctx,
    float* __restrict__ c2) {
  int b = blockIdx.x;
  int h = threadIdx.x;
  __shared__ float sc[H_];
  sc[h] = ctx[b * H_ + h];
  __syncthreads();
  const float* wr = W2 + h * 256 + 128;
  float acc = 0.f;
  #pragma unroll 4
  for (int k = 0; k < 128; ++k) acc += wr[k] * sc[k];
  c2[b * H_ + h] = acc;
}

// Stage 2 (frag-layout wsT path). grid (32, B): s-chunk 64, 4 waves,
// wave w owns W2 m-tiles {2w, 2w+1} in registers; B-frags staged via gl_lds.
__global__ __launch_bounds__(256) void stage2T(
    const unsigned short* __restrict__ wsT, const unsigned short* __restrict__ wsA,
    const float* __restrict__ c2, const float* __restrict__ v2,
    const unsigned char* __restrict__ mask8, const int* __restrict__ flag,
    float* __restrict__ score) {
  const int b = blockIdx.y;
  const int tid = threadIdx.x;
  const int lane = tid & 63, w = tid >> 6, g = lane >> 4, li = lane & 15;
  __shared__ unsigned short frag[4][4][512];  // [stile][t][lane*8]
  __shared__ float spart[256];
  __shared__ float sc2[H_], sv2[H_];

  const int schunk = blockIdx.x * 64;

  short8 aW[2][4];
  #pragma unroll
  for (int mm = 0; mm < 2; ++mm)
    #pragma unroll
    for (int t = 0; t < 4; ++t)
      aW[mm][t] = *(const short8*)(wsA + (size_t)(((8 + 2 * w + mm) * 4 + t) * 64 + lane) * 8);

  // wave w stages s-tile w (4 x 1KB contiguous)
  {
    size_t base = ((size_t)b * (S_ / 16) + (schunk >> 4) + w) * 4 * 512;
    #pragma unroll
    for (int t = 0; t < 4; ++t) {
      const unsigned short* src = wsT + base + t * 512 + lane * 8;
      __builtin_amdgcn_global_load_lds((gvoid_t*)src, (lvoid_t*)&frag[w][t][0], 16, 0, 0);
    }
  }

  if (tid < 128) { sc2[tid] = c2[b * H_ + tid]; sv2[tid] = v2[tid]; }
  __syncthreads();

  f32x4 acc[4][2];
  #pragma unroll
  for (int st = 0; st < 4; ++st) { acc[st][0] = (f32x4)0.0f; acc[st][1] = (f32x4)0.0f; }
  #pragma unroll
  for (int st = 0; st < 4; ++st)
    #pragma unroll
    for (int t = 0; t < 4; ++t) {
      short8 bS = *(const short8*)&frag[st][t][lane * 8];
      acc[st][0] = __builtin_amdgcn_mfma_f32_16x16x32_bf16(aW[0][t], bS, acc[st][0], 0, 0, 0);
      acc[st][1] = __builtin_amdgcn_mfma_f32_16x16x32_bf16(aW[1][t], bS, acc[st][1], 0, 0, 0);
    }

  #pragma unroll
  for (int st = 0; st < 4; ++st) {
    float part = 0.f;
    #pragma unroll
    for (int mm = 0; mm < 2; ++mm)
      #pragma unroll
      for (int r = 0; r < 4; ++r) {
        int h = 32 * w + 16 * mm + 4 * g + r;
        part += sv2[h] * tanh_fast(acc[st][mm][r] + sc2[h]);
      }
    part += __shfl_xor(part, 16);
    part += __shfl_xor(part, 32);
    if (lane < 16) spart[w * 64 + st * 16 + li] = part;
  }
  __syncthreads();

  if (tid < 64) {
    float tot = spart[tid] + spart[64 + tid] + spart[128 + tid] + spart[192 + tid];
    size_t mi = (size_t)b * S_ + schunk + tid;
    int f = *flag;
    bool msk;
    if (f == 1)      msk = mask8[mi] != 0;
    else if (f == 2) msk = ((const float*)mask8)[mi] != 0.0f;
    else             msk = ((const int*)mask8)[mi] != 0;
    score[mi] = msk ? -INFINITY : tot;
  }
}

// Stage 2 fallback (f32 path, no wsT). grid (32, B), s-chunk 64.
__global__ __launch_bounds__(256) void stage2F(
    const float* __restrict__ sEmb, const unsigned short* __restrict__ wsA,
    const float* __restrict__ c2, const float* __restrict__ v2,
    const unsigned char* __restrict__ mask8, const int* __restrict__ flag,
    float* __restrict__ score) {
  int b = blockIdx.y;
  int tid = threadIdx.x;
  int lane = tid & 63, w = tid >> 6, g = lane >> 4, li = lane & 15;
  __shared__ float sS[128 * 64];
  __shared__ float sc2[H_], sv2[H_];
  __shared__ float spart[256];

  const int schunk = blockIdx.x * 64;
  const size_t sbase = (size_t)b * H_ * S_;

  short8 aW[2][4];
  #pragma unroll
  for (int mm = 0; mm < 2; ++mm)
    #pragma unroll
    for (int t = 0; t < 4; ++t)
      aW[mm][t] = *(const short8*)(wsA + (size_t)(((8 + 2 * w + mm) * 4 + t) * 64 + lane) * 8);

  {
    int lrow = lane >> 4, lcol4 = 4 * (lane & 15);
    #pragma unroll
    for (int i = 0; i < 8; ++i) {
      int r = 32 * w + 4 * i + lrow;
      int gcol = lcol4 ^ (((r >> 3) & 3) << 3);
      const float* src = sEmb + sbase + (size_t)r * S_ + schunk + gcol;
      __builtin_amdgcn_global_load_lds((gvoid_t*)src, (lvoid_t*)&sS[(32 * w + 4 * i) * 64],
                                       16, 0, 0);
    }
  }

  if (tid < 128) { sc2[tid] = c2[b * H_ + tid]; sv2[tid] = v2[tid]; }
  __syncthreads();

  f32x4 acc[4][2];
  #pragma unroll
  for (int st = 0; st < 4; ++st) { acc[st][0] = (f32x4)0.0f; acc[st][1] = (f32x4)0.0f; }

  #pragma unroll
  for (int st = 0; st < 4; ++st) {
    const int colA = (16 * st + li) ^ (g << 3);
    #pragma unroll
    for (int t = 0; t < 4; ++t) {
      short8 bS;
      #pragma unroll
      for (int j = 0; j < 8; ++j)
        bS[j] = (short)f2bf(sS[(32 * t + 8 * g + j) * 64 + colA]);
      acc[st][0] = __builtin_amdgcn_mfma_f32_16x16x32_bf16(aW[0][t], bS, acc[st][0], 0, 0, 0);
      acc[st][1] = __builtin_amdgcn_mfma_f32_16x16x32_bf16(aW[1][t], bS, acc[st][1], 0, 0, 0);
    }
  }

  #pragma unroll
  for (int st = 0; st < 4; ++st) {
    float part = 0.f;
    #pragma unroll
    for (int mm = 0; mm < 2; ++mm)
      #pragma unroll
      for (int r = 0; r < 4; ++r) {
        int h = 32 * w + 16 * mm + 4 * g + r;
        part += sv2[h] * tanh_fast(acc[st][mm][r] + sc2[h]);
      }
    part += __shfl_xor(part, 16);
    part += __shfl_xor(part, 32);
    if (lane < 16) spart[w * 64 + st * 16 + li] = part;
  }
  __syncthreads();

  if (tid < 64) {
    float tot = spart[tid] + spart[64 + tid] + spart[128 + tid] + spart[192 + tid];
    size_t mi = (size_t)b * S_ + schunk + tid;
    int f = *flag;
    bool msk;
    if (f == 1)      msk = mask8[mi] != 0;
    else if (f == 2) msk = ((const float*)mask8)[mi] != 0.0f;
    else             msk = ((const int*)mask8)[mi] != 0;
    score[mi] = msk ? -INFINITY : tot;
  }
}

// Final row softmax -> out
__global__ __launch_bounds__(256) void ksoftmax(
    const float* __restrict__ score, float* __restrict__ out) {
  int b = blockIdx.x;
  int tid = threadIdx.x, lane = tid & 63, w = tid >> 6;
  __shared__ float wred[4];
  __shared__ float sred;
  float a[8];
  #pragma unroll
  for (int i = 0; i < 8; ++i) a[i] = score[(size_t)b * S_ + i * 256 + tid];
  float mx = a[0];
  #pragma unroll
  for (int i = 1; i < 8; ++i) mx = fmaxf(mx, a[i]);
  #pragma unroll
  for (int off = 32; off >= 1; off >>= 1) mx = fmaxf(mx, __shfl_xor(mx, off));
  if (lane == 0) wred[w] = mx;
  __syncthreads();
  if (tid == 0) sred = fmaxf(fmaxf(wred[0], wred[1]), fmaxf(wred[2], wred[3]));
  __syncthreads();
  mx = sred;
  __syncthreads();
  float e[8];
  float sum = 0.f;
  #pragma unroll
  for (int i = 0; i < 8; ++i) { e[i] = __expf(a[i] - mx); sum += e[i]; }
  #pragma unroll
  for (int off = 32; off >= 1; off >>= 1) sum += __shfl_xor(sum, off);
  if (lane == 0) wred[w] = sum;
  __syncthreads();
  if (tid == 0) sred = 1.0f / (wred[0] + wred[1] + wred[2] + wred[3]);
  __syncthreads();
  float inv = sred;
  #pragma unroll
  for (int i = 0; i < 8; ++i) out[(size_t)b * S_ + i * 256 + tid] = e[i] * inv;
}

extern "C" void kernel_launch(void* const* d_in, const int* in_sizes, int n_in,
                              void* d_out, int out_size, void* d_ws, size_t ws_size,
                              hipStream_t stream) {
  (void)in_sizes; (void)n_in; (void)out_size;
  if (ws_size < WS_NEED) return;
  const float* sEmb = (const float*)d_in[0];
  const float* dEmb = (const float*)d_in[1];
  const float* dec  = (const float*)d_in[2];
  const unsigned char* mask = (const unsigned char*)d_in[3];
  const float* v    = (const float*)d_in[4];
  const float* W    = (const float*)d_in[5];
  const float* v2   = (const float*)d_in[6];
  const float* W2   = (const float*)d_in[7];

  char* ws = (char*)d_ws;
  unsigned short* wsA = (unsigned short*)(ws);
  int*   flag  = (int*)  (ws + 114688);
  float* c1    = (float*)(ws + 131072);
  float* c2    = (float*)(ws + 262144);
  float* ctx   = (float*)(ws + 393216);
  float* attns = (float*)(ws + 524288);
  float* score = (float*)(ws + 2621440);
  bool useT = (ws_size >= WS_T_NEED);
  unsigned short* wsT = useT ? (unsigned short*)(ws + WST_OFF) : nullptr;

  prep_wfrags<<<192, 256, 0, stream>>>(W, W2, wsA);
  prep_c1<<<B_, 128, 0, stream>>>(W, dec, c1);
  detect_mask<<<1, 256, 0, stream>>>(mask, flag);
  stage1<<<dim3(4, B_), 256, 0, stream>>>(sEmb, dEmb, wsA, c1, v, attns, wsT);
  kmid_a<<<dim3(4, B_), 256, 0, stream>>>(attns, sEmb, ctx);
  kmid_b<<<B_, 128, 0, stream>>>(W2, ctx, c2);
  if (useT)
    stage2T<<<dim3(32, B_), 256, 0, stream>>>(wsT, wsA, c2, v2, mask, flag, score);
  else
    stage2F<<<dim3(32, B_), 256, 0, stream>>>(sEmb, wsA, c2, v2, mask, flag, score);
  ksoftmax<<<B_, 256, 0, stream>>>(score, (float*)d_out);
}

// Round 5
// 229.902 us; speedup vs baseline: 1.4781x; 1.2461x over previous
//
#include <hip/hip_runtime.h>
#include <stdint.h>
#include <math.h>

#define B_ 256
#define H_ 128
#define S_ 2048

typedef __attribute__((ext_vector_type(8))) short short8;
typedef __attribute__((ext_vector_type(4))) float f32x4;
typedef __attribute__((ext_vector_type(4))) unsigned int u32x4;

typedef const __attribute__((address_space(1))) void gvoid_t;
typedef __attribute__((address_space(3))) void lvoid_t;

// ---------- helpers ----------
__device__ __forceinline__ unsigned short f2bf(float f) {
  uint32_t u = __builtin_bit_cast(uint32_t, f);
  u += 0x7fffu + ((u >> 16) & 1u);          // round-to-nearest-even
  return (unsigned short)(u >> 16);
}

// pack 2 f32 -> 2 bf16 (RNE), 1 VALU op
__device__ __forceinline__ uint32_t cvtpk(float lo, float hi) {
  uint32_t r;
  asm("v_cvt_pk_bf16_f32 %0, %1, %2" : "=v"(r) : "v"(lo), "v"(hi));
  return r;
}

__device__ __forceinline__ float bf2f(unsigned short u) {
  return __builtin_bit_cast(float, (uint32_t)u << 16);
}

// tanh(x) = 1 - 2/(1+e^{2x}); correct limits at +-inf, ~1e-6 abs err. 5 VALU ops.
__device__ __forceinline__ float tanh5(float x) {
  float e = __builtin_amdgcn_exp2f(x * 2.8853900817779268f);
  float r = __builtin_amdgcn_rcpf(1.0f + e);
  return fmaf(-2.0f, r, 1.0f);
}

// ---------- ws layout (bytes) ----------
// wsA frags : [0, 98304)          24 tiles x 4 ksteps x 64 lanes x 8 bf16
// flag      : [114688, 114692)
// c1        : [131072, 262144)    [B,H] f32
// c2        : [262144, 393216)    [B,H] f32
// ctx       : [393216, 524288)    [B,H] f32
// attns     : [524288, 2621440)   [B,S] f32
// score     : [2621440, 4718592)  [B,S] f32
// wsT       : [8388608, +134217728)  bf16 static in MFMA B-frag layout:
//             [b][stile(S/16)][t(4)][lane(64)][8]
#define WS_NEED 4718592u
#define WST_OFF 8388608u
#define WS_T_NEED (WST_OFF + (size_t)B_ * (S_/16) * 4 * 64 * 8 * 2)

__global__ __launch_bounds__(256) void prep_wfrags(
    const float* __restrict__ W, const float* __restrict__ W2,
    unsigned short* __restrict__ wsA) {
  int idx = blockIdx.x * 256 + threadIdx.x;   // 24*4*64*8 = 49152 total
  if (idx >= 24 * 4 * 64 * 8) return;
  int j = idx & 7;
  int lane = (idx >> 3) & 63;
  int t = (idx >> 9) & 3;
  int tile = idx >> 11;
  int li = lane & 15;
  int k = t * 32 + (lane >> 4) * 8 + j;
  float val;
  if (tile < 8)        val = W[(tile * 16 + li) * 384 + k];             // W_a
  else if (tile < 16)  val = W2[((tile - 8) * 16 + li) * 256 + k];      // W2_a
  else                 val = W[((tile - 16) * 16 + li) * 384 + 128 + k];// W_b
  wsA[idx] = f2bf(val);
}

// c1[b,h] = sum_k W[h, 256+k] * dec[b,k]
__global__ __launch_bounds__(128) void prep_c1(
    const float* __restrict__ W, const float* __restrict__ dec,
    float* __restrict__ c1) {
  int b = blockIdx.x;
  int h = threadIdx.x;
  __shared__ float sdec[H_];
  sdec[h] = dec[b * H_ + h];
  __syncthreads();
  const float* wr = W + h * 384 + 256;
  float acc = 0.f;
  #pragma unroll 4
  for (int k = 0; k < 128; ++k) acc += wr[k] * sdec[k];
  c1[b * H_ + h] = acc;
}

// Detect mask element width: 0 = int32, 1 = uint8(bool), 2 = float32.
__global__ void detect_mask(const unsigned char* __restrict__ mb, int* __restrict__ flag) {
  __shared__ int sGT1, sNZ;
  if (threadIdx.x == 0) { sGT1 = 0; sNZ = 0; }
  __syncthreads();
  int gt1 = 0, nz = 0;
  for (int i = threadIdx.x; i < 8192; i += 256) {
    unsigned char c = mb[i];
    if (c > 1) gt1 = 1;
    if ((i & 3) && c) nz = 1;
  }
  if (gt1) atomicOr(&sGT1, 1);
  if (nz)  atomicOr(&sNZ, 1);
  __syncthreads();
  if (threadIdx.x == 0) *flag = sGT1 ? 2 : (sNZ ? 1 : 0);
}

// Stage 1. grid (4, B): block owns 512 s (8 chunks of 64); 4 waves; wave w owns
// h m-tiles {2w,2w+1} (W frags in regs, loaded once). LDS 67.6 KB -> 2 blocks/CU.
// Per chunk: wave w converts s-tile w (static from LDS, dyn from regs) into the
// shared frag buffer + streams static frags to wsT; prefetch overlaps MFMA.
__global__ __launch_bounds__(256) void stage1(
    const float* __restrict__ sEmb, const float* __restrict__ dEmb,
    const unsigned short* __restrict__ wsA, const float* __restrict__ c1,
    const float* __restrict__ v, float* __restrict__ attns,
    unsigned short* __restrict__ wsT) {
  const int b = blockIdx.y;
  const int tid = threadIdx.x;
  const int lane = tid & 63, w = tid >> 6, g = lane >> 4, li = lane & 15;
  __shared__ float sS[128 * 64];              // [k][s] f32, stored col = s ^ (g-bits swz)
  __shared__ unsigned short frag[4][8][512];  // [stile][t | 4+t][lane*8] bf16
  __shared__ float spart[256];
  __shared__ float sc1[H_], sv[H_];

  const size_t sbase = (size_t)b * H_ * S_;
  const size_t dbase = (size_t)b * S_ * H_;
  const int sblk = blockIdx.x * 512;

  // W fragments -> registers (once)
  short8 aW[2][4], aB[2][4];
  #pragma unroll
  for (int mm = 0; mm < 2; ++mm)
    #pragma unroll
    for (int t = 0; t < 4; ++t) {
      aW[mm][t] = *(const short8*)(wsA + (size_t)(((2 * w + mm) * 4 + t) * 64 + lane) * 8);
      aB[mm][t] = *(const short8*)(wsA + (size_t)(((16 + 2 * w + mm) * 4 + t) * 64 + lane) * 8);
    }
  if (tid < 128) { sc1[tid] = c1[b * H_ + tid]; sv[tid] = v[tid]; }

  const int lrow = lane >> 4, lcol4 = 4 * (lane & 15);
  auto stageS = [&](int soff) {
    #pragma unroll
    for (int i = 0; i < 8; ++i) {
      int r = 32 * w + 4 * i + lrow;
      int gcol = lcol4 ^ (((r >> 3) & 3) << 3);
      const float* src = sEmb + sbase + (size_t)r * S_ + soff + gcol;
      __builtin_amdgcn_global_load_lds((gvoid_t*)src, (lvoid_t*)&sS[(32 * w + 4 * i) * 64],
                                       16, 0, 0);
    }
  };
  f32x4 dv[8];
  auto loadD = [&](int soff) {
    const float* dr = dEmb + dbase + (size_t)(soff + 16 * w + li) * H_ + 8 * g;
    #pragma unroll
    for (int t = 0; t < 4; ++t) {
      dv[2 * t]     = *(const f32x4*)(dr + 32 * t);
      dv[2 * t + 1] = *(const f32x4*)(dr + 32 * t + 4);
    }
  };

  stageS(sblk);
  loadD(sblk);

  const int colA = (16 * w + li) ^ (g << 3);

  for (int c = 0; c < 8; ++c) {
    const int soff = sblk + c * 64;
    __syncthreads();                          // A: sS(c)+dv landed; frag free; spart(c-1) done
    if (c > 0 && tid < 64)
      attns[(size_t)b * S_ + soff - 64 + tid] =
          spart[tid] + spart[64 + tid] + spart[128 + tid] + spart[192 + tid];

    // convert: wave w builds s-tile w's B-frags (static + dyn)
    #pragma unroll
    for (int t = 0; t < 4; ++t) {
      const int rb = (32 * t + 8 * g) * 64 + colA;
      uint32_t s0 = cvtpk(sS[rb], sS[rb + 64]);
      uint32_t s1 = cvtpk(sS[rb + 128], sS[rb + 192]);
      uint32_t s2 = cvtpk(sS[rb + 256], sS[rb + 320]);
      uint32_t s3 = cvtpk(sS[rb + 384], sS[rb + 448]);
      u32x4 us = {s0, s1, s2, s3};
      short8 bS = __builtin_bit_cast(short8, us);
      uint32_t d0 = cvtpk(dv[2 * t].x, dv[2 * t].y);
      uint32_t d1 = cvtpk(dv[2 * t].z, dv[2 * t].w);
      uint32_t d2 = cvtpk(dv[2 * t + 1].x, dv[2 * t + 1].y);
      uint32_t d3 = cvtpk(dv[2 * t + 1].z, dv[2 * t + 1].w);
      u32x4 ud = {d0, d1, d2, d3};
      short8 bD = __builtin_bit_cast(short8, ud);
      *(short8*)&frag[w][t][lane * 8] = bS;
      *(short8*)&frag[w][4 + t][lane * 8] = bD;
      if (wsT)
        *(short8*)&wsT[(((size_t)b * (S_ / 16) + (soff >> 4) + w) * 4 + t) * 512 + lane * 8] = bS;
    }
    __syncthreads();                          // B: frags visible; sS/dv consumed
    if (c + 1 < 8) { stageS(soff + 64); loadD(soff + 64); }

    // MFMA phase
    f32x4 acc[4][2];
    #pragma unroll
    for (int st = 0; st < 4; ++st) { acc[st][0] = (f32x4)0.0f; acc[st][1] = (f32x4)0.0f; }
    #pragma unroll
    for (int st = 0; st < 4; ++st)
      #pragma unroll
      for (int t = 0; t < 4; ++t) {
        short8 bS = *(const short8*)&frag[st][t][lane * 8];
        short8 bD = *(const short8*)&frag[st][4 + t][lane * 8];
        acc[st][0] = __builtin_amdgcn_mfma_f32_16x16x32_bf16(aW[0][t], bS, acc[st][0], 0, 0, 0);
        acc[st][1] = __builtin_amdgcn_mfma_f32_16x16x32_bf16(aW[1][t], bS, acc[st][1], 0, 0, 0);
        acc[st][0] = __builtin_amdgcn_mfma_f32_16x16x32_bf16(aB[0][t], bD, acc[st][0], 0, 0, 0);
        acc[st][1] = __builtin_amdgcn_mfma_f32_16x16x32_bf16(aB[1][t], bD, acc[st][1], 0, 0, 0);
      }

    // epilogue: partial v-dot over this wave's 32 h
    #pragma unroll
    for (int st = 0; st < 4; ++st) {
      float part = 0.f;
      #pragma unroll
      for (int mm = 0; mm < 2; ++mm)
        #pragma unroll
        for (int r = 0; r < 4; ++r) {
          int h = 32 * w + 16 * mm + 4 * g + r;
          part += sv[h] * tanh5(acc[st][mm][r] + sc1[h]);
        }
      part += __shfl_xor(part, 16);
      part += __shfl_xor(part, 32);
      if (lane < 16) spart[w * 64 + st * 16 + li] = part;
    }
  }
  __syncthreads();
  if (tid < 64)
    attns[(size_t)b * S_ + sblk + 448 + tid] =
        spart[tid] + spart[64 + tid] + spart[128 + tid] + spart[192 + tid];
}

// Fused tail (wsT path): softmax1 + context(from wsT) + c2 + stage2 scores (MFMA
// from wsT) + mask + final softmax. One block per batch, 512 threads (8 waves).
__global__ __launch_bounds__(512) void fuse2(
    const float* __restrict__ attns, const unsigned short* __restrict__ wsT,
    const unsigned short* __restrict__ wsA, const float* __restrict__ W2,
    const float* __restrict__ v2, const unsigned char* __restrict__ mask8,
    const int* __restrict__ flag, float* __restrict__ out) {
  const int b = blockIdx.x;
  const int tid = threadIdx.x;
  const int lane = tid & 63, wv = tid >> 6, g = lane >> 4, li = lane & 15;
  __shared__ float buf[S_];         // p, later scores
  __shared__ float sctx[8][H_];
  __shared__ float2 sq[H_];         // (c2[h], v2[h])
  __shared__ float wred[8];
  __shared__ float sred;

  const size_t pbase = (size_t)b * (S_ / 16);

  // ---- Phase A: softmax(attns row) -> buf = exp(a-mx), inv1 ----
  float a[4];
  #pragma unroll
  for (int i = 0; i < 4; ++i) a[i] = attns[(size_t)b * S_ + i * 512 + tid];
  float mx = fmaxf(fmaxf(a[0], a[1]), fmaxf(a[2], a[3]));
  #pragma unroll
  for (int off = 32; off >= 1; off >>= 1) mx = fmaxf(mx, __shfl_xor(mx, off));
  if (lane == 0) wred[wv] = mx;
  __syncthreads();
  if (tid == 0) {
    float m = wred[0];
    #pragma unroll
    for (int i = 1; i < 8; ++i) m = fmaxf(m, wred[i]);
    sred = m;
  }
  __syncthreads();
  mx = sred;
  __syncthreads();
  float sum = 0.f;
  #pragma unroll
  for (int i = 0; i < 4; ++i) {
    float e = __expf(a[i] - mx);
    buf[i * 512 + tid] = e;
    sum += e;
  }
  #pragma unroll
  for (int off = 32; off >= 1; off >>= 1) sum += __shfl_xor(sum, off);
  if (lane == 0) wred[wv] = sum;
  __syncthreads();
  if (tid == 0) {
    float s = 0.f;
    #pragma unroll
    for (int i = 0; i < 8; ++i) s += wred[i];
    sred = 1.0f / s;
  }
  __syncthreads();
  const float inv1 = sred;
  __syncthreads();

  // ---- Phase B: ctx partials from wsT (wave wv: stiles wv, wv+8, ...) ----
  float hacc[4][8];
  #pragma unroll
  for (int t = 0; t < 4; ++t)
    #pragma unroll
    for (int j = 0; j < 8; ++j) hacc[t][j] = 0.f;
  short8 cur[4];
  #pragma unroll
  for (int t = 0; t < 4; ++t)
    cur[t] = *(const short8*)&wsT[((pbase + wv) * 4 + t) * 512 + lane * 8];
  for (int stile = wv; stile < 128; stile += 8) {
    short8 nxt[4];
    const bool more = (stile + 8) < 128;
    if (more) {
      #pragma unroll
      for (int t = 0; t < 4; ++t)
        nxt[t] = *(const short8*)&wsT[((pbase + stile + 8) * 4 + t) * 512 + lane * 8];
    }
    float pw = buf[stile * 16 + li];
    #pragma unroll
    for (int t = 0; t < 4; ++t)
      #pragma unroll
      for (int j = 0; j < 8; ++j)
        hacc[t][j] = fmaf(pw, bf2f((unsigned short)cur[t][j]), hacc[t][j]);
    if (more) {
      #pragma unroll
      for (int t = 0; t < 4; ++t) cur[t] = nxt[t];
    }
  }
  #pragma unroll
  for (int t = 0; t < 4; ++t)
    #pragma unroll
    for (int j = 0; j < 8; ++j) {
      float x = hacc[t][j];
      x += __shfl_xor(x, 1); x += __shfl_xor(x, 2);
      x += __shfl_xor(x, 4); x += __shfl_xor(x, 8);
      hacc[t][j] = x;
    }
  if (li == 0) {
    #pragma unroll
    for (int t = 0; t < 4; ++t)
      #pragma unroll
      for (int j = 0; j < 8; ++j)
        sctx[wv][32 * t + 8 * g + j] = hacc[t][j];
  }
  __syncthreads();

  // ---- Phase C: ctx reduce + c2 + (c2,v2) pack ----
  if (tid < 128) {
    float cx = 0.f;
    #pragma unroll
    for (int q = 0; q < 8; ++q) cx += sctx[q][tid];
    sctx[0][tid] = cx * inv1;
  }
  __syncthreads();
  if (tid < 128) {
    const float* wr = W2 + tid * 256 + 128;
    float c2v = 0.f;
    #pragma unroll 4
    for (int k = 0; k < 128; ++k) c2v += wr[k] * sctx[0][k];
    sq[tid] = make_float2(c2v, v2[tid]);
  }
  __syncthreads();

  // ---- Phase D: stage-2 scores, s-split waves, all W2a in regs ----
  short8 aW[8][4];
  #pragma unroll
  for (int m = 0; m < 8; ++m)
    #pragma unroll
    for (int t = 0; t < 4; ++t)
      aW[m][t] = *(const short8*)(wsA + (size_t)(((8 + m) * 4 + t) * 64 + lane) * 8);
  const int f = *flag;

  short8 bcur[4];
  #pragma unroll
  for (int t = 0; t < 4; ++t)
    bcur[t] = *(const short8*)&wsT[((pbase + wv) * 4 + t) * 512 + lane * 8];
  for (int stile = wv; stile < 128; stile += 8) {
    short8 bnxt[4];
    const bool more = (stile + 8) < 128;
    if (more) {
      #pragma unroll
      for (int t = 0; t < 4; ++t)
        bnxt[t] = *(const short8*)&wsT[((pbase + stile + 8) * 4 + t) * 512 + lane * 8];
    }
    f32x4 acc[8];
    #pragma unroll
    for (int m = 0; m < 8; ++m) acc[m] = (f32x4)0.0f;
    #pragma unroll
    for (int t = 0; t < 4; ++t)
      #pragma unroll
      for (int m = 0; m < 8; ++m)
        acc[m] = __builtin_amdgcn_mfma_f32_16x16x32_bf16(aW[m][t], bcur[t], acc[m], 0, 0, 0);
    float part = 0.f;
    #pragma unroll
    for (int m = 0; m < 8; ++m)
      #pragma unroll
      for (int r = 0; r < 4; ++r) {
        float2 q = sq[16 * m + 4 * g + r];
        part += q.y * tanh5(acc[m][r] + q.x);
      }
    part += __shfl_xor(part, 16);
    part += __shfl_xor(part, 32);
    if (lane < 16) {
      int s = stile * 16 + li;
      size_t mi = (size_t)b * S_ + s;
      bool msk;
      if (f == 1)      msk = mask8[mi] != 0;
      else if (f == 2) msk = ((const float*)mask8)[mi] != 0.0f;
      else             msk = ((const int*)mask8)[mi] != 0;
      buf[s] = msk ? -INFINITY : part;
    }
    if (more) {
      #pragma unroll
      for (int t = 0; t < 4; ++t) bcur[t] = bnxt[t];
    }
  }
  __syncthreads();

  // ---- Phase E: final softmax buf -> out ----
  float s4[4];
  #pragma unroll
  for (int i = 0; i < 4; ++i) s4[i] = buf[i * 512 + tid];
  float mx2 = fmaxf(fmaxf(s4[0], s4[1]), fmaxf(s4[2], s4[3]));
  #pragma unroll
  for (int off = 32; off >= 1; off >>= 1) mx2 = fmaxf(mx2, __shfl_xor(mx2, off));
  if (lane == 0) wred[wv] = mx2;
  __syncthreads();
  if (tid == 0) {
    float m = wred[0];
    #pragma unroll
    for (int i = 1; i < 8; ++i) m = fmaxf(m, wred[i]);
    sred = m;
  }
  __syncthreads();
  mx2 = sred;
  __syncthreads();
  float e4[4];
  float sum2 = 0.f;
  #pragma unroll
  for (int i = 0; i < 4; ++i) { e4[i] = __expf(s4[i] - mx2); sum2 += e4[i]; }
  #pragma unroll
  for (int off = 32; off >= 1; off >>= 1) sum2 += __shfl_xor(sum2, off);
  if (lane == 0) wred[wv] = sum2;
  __syncthreads();
  if (tid == 0) {
    float s = 0.f;
    #pragma unroll
    for (int i = 0; i < 8; ++i) s += wred[i];
    sred = 1.0f / s;
  }
  __syncthreads();
  const float inv2 = sred;
  #pragma unroll
  for (int i = 0; i < 4; ++i) out[(size_t)b * S_ + i * 512 + tid] = e4[i] * inv2;
}

// ================= fallback path (no wsT) — unchanged from R4 =================
__global__ __launch_bounds__(256) void kmid_a(
    const float* __restrict__ attns, const float* __restrict__ sEmb,
    float* __restrict__ ctx) {
  int q = blockIdx.x, b = blockIdx.y;
  int tid = threadIdx.x, lane = tid & 63, w = tid >> 6;
  __shared__ float p[S_];
  __shared__ float wred[4];
  __shared__ float sred;
  float a[8];
  #pragma unroll
  for (int i = 0; i < 8; ++i) a[i] = attns[(size_t)b * S_ + i * 256 + tid];
  float mx = a[0];
  #pragma unroll
  for (int i = 1; i < 8; ++i) mx = fmaxf(mx, a[i]);
  #pragma unroll
  for (int off = 32; off >= 1; off >>= 1) mx = fmaxf(mx, __shfl_xor(mx, off));
  if (lane == 0) wred[w] = mx;
  __syncthreads();
  if (tid == 0) sred = fmaxf(fmaxf(wred[0], wred[1]), fmaxf(wred[2], wred[3]));
  __syncthreads();
  mx = sred;
  __syncthreads();
  float sum = 0.f;
  #pragma unroll
  for (int i = 0; i < 8; ++i) {
    float e = __expf(a[i] - mx);
    p[i * 256 + tid] = e;
    sum += e;
  }
  #pragma unroll
  for (int off = 32; off >= 1; off >>= 1) sum += __shfl_xor(sum, off);
  if (lane == 0) wred[w] = sum;
  __syncthreads();
  if (tid == 0) sred = 1.0f / (wred[0] + wred[1] + wred[2] + wred[3]);
  __syncthreads();
  float inv = sred;
  #pragma unroll
  for (int hh = 0; hh < 8; ++hh) {
    int h = q * 32 + w * 8 + hh;
    const f32x4* xp = (const f32x4*)(sEmb + (size_t)b * H_ * S_ + (size_t)h * S_);
    float av = 0.f;
    #pragma unroll
    for (int it = 0; it < 8; ++it) {
      f32x4 x = xp[it * 64 + lane];
      f32x4 pp = *(const f32x4*)&p[(it * 64 + lane) * 4];
      av += x.x * pp.x + x.y * pp.y + x.z * pp.z + x.w * pp.w;
    }
    #pragma unroll
    for (int off = 32; off >= 1; off >>= 1) av += __shfl_xor(av, off);
    if (lane == 0) ctx[b * H_ + h] = av * inv;
  }
}

__global__ __launch_bounds__(128) void kmid_b(
    const float* __restrict__ W2, const float* __restrict__ ctx,
    float* __restrict__ c2) {
  int b = blockIdx.x;
  int h = threadIdx.x;
  __shared__ float sc[H_];
  sc[h] = ctx[b * H_ + h];
  __syncthreads();
  const float* wr = W2 + h * 256 + 128;
  float acc = 0.f;
  #pragma unroll 4
  for (int k = 0; k < 128; ++k) acc += wr[k] * sc[k];
  c2[b * H_ + h] = acc;
}

__global__ __launch_bounds__(256) void stage2F(
    const float* __restrict__ sEmb, const unsigned short* __restrict__ wsA,
    const float* __restrict__ c2, const float* __restrict__ v2,
    const unsigned char* __restrict__ mask8, const int* __restrict__ flag,
    float* __restrict__ score) {
  int b = blockIdx.y;
  int tid = threadIdx.x;
  int lane = tid & 63, w = tid >> 6, g = lane >> 4, li = lane & 15;
  __shared__ float sS[128 * 64];
  __shared__ float sc2[H_], sv2[H_];
  __shared__ float spart[256];
  const int schunk = blockIdx.x * 64;
  const size_t sbase = (size_t)b * H_ * S_;
  short8 aW[2][4];
  #pragma unroll
  for (int mm = 0; mm < 2; ++mm)
    #pragma unroll
    for (int t = 0; t < 4; ++t)
      aW[mm][t] = *(const short8*)(wsA + (size_t)(((8 + 2 * w + mm) * 4 + t) * 64 + lane) * 8);
  {
    int lrow = lane >> 4, lcol4 = 4 * (lane & 15);
    #pragma unroll
    for (int i = 0; i < 8; ++i) {
      int r = 32 * w + 4 * i + lrow;
      int gcol = lcol4 ^ (((r >> 3) & 3) << 3);
      const float* src = sEmb + sbase + (size_t)r * S_ + schunk + gcol;
      __builtin_amdgcn_global_load_lds((gvoid_t*)src, (lvoid_t*)&sS[(32 * w + 4 * i) * 64],
                                       16, 0, 0);
    }
  }
  if (tid < 128) { sc2[tid] = c2[b * H_ + tid]; sv2[tid] = v2[tid]; }
  __syncthreads();
  f32x4 acc[4][2];
  #pragma unroll
  for (int st = 0; st < 4; ++st) { acc[st][0] = (f32x4)0.0f; acc[st][1] = (f32x4)0.0f; }
  #pragma unroll
  for (int st = 0; st < 4; ++st) {
    const int colA = (16 * st + li) ^ (g << 3);
    #pragma unroll
    for (int t = 0; t < 4; ++t) {
      short8 bS;
      #pragma unroll
      for (int j = 0; j < 8; ++j)
        bS[j] = (short)f2bf(sS[(32 * t + 8 * g + j) * 64 + colA]);
      acc[st][0] = __builtin_amdgcn_mfma_f32_16x16x32_bf16(aW[0][t], bS, acc[st][0], 0, 0, 0);
      acc[st][1] = __builtin_amdgcn_mfma_f32_16x16x32_bf16(aW[1][t], bS, acc[st][1], 0, 0, 0);
    }
  }
  #pragma unroll
  for (int st = 0; st < 4; ++st) {
    float part = 0.f;
    #pragma unroll
    for (int mm = 0; mm < 2; ++mm)
      #pragma unroll
      for (int r = 0; r < 4; ++r) {
        int h = 32 * w + 16 * mm + 4 * g + r;
        part += sv2[h] * tanh5(acc[st][mm][r] + sc2[h]);
      }
    part += __shfl_xor(part, 16);
    part += __shfl_xor(part, 32);
    if (lane < 16) spart[w * 64 + st * 16 + li] = part;
  }
  __syncthreads();
  if (tid < 64) {
    float tot = spart[tid] + spart[64 + tid] + spart[128 + tid] + spart[192 + tid];
    size_t mi = (size_t)b * S_ + schunk + tid;
    int f = *flag;
    bool msk;
    if (f == 1)      msk = mask8[mi] != 0;
    else if (f == 2) msk = ((const float*)mask8)[mi] != 0.0f;
    else             msk = ((const int*)mask8)[mi] != 0;
    score[mi] = msk ? -INFINITY : tot;
  }
}

__global__ __launch_bounds__(256) void ksoftmax(
    const float* __restrict__ score, float* __restrict__ out) {
  int b = blockIdx.x;
  int tid = threadIdx.x, lane = tid & 63, w = tid >> 6;
  __shared__ float wred[4];
  __shared__ float sred;
  float a[8];
  #pragma unroll
  for (int i = 0; i < 8; ++i) a[i] = score[(size_t)b * S_ + i * 256 + tid];
  float mx = a[0];
  #pragma unroll
  for (int i = 1; i < 8; ++i) mx = fmaxf(mx, a[i]);
  #pragma unroll
  for (int off = 32; off >= 1; off >>= 1) mx = fmaxf(mx, __shfl_xor(mx, off));
  if (lane == 0) wred[w] = mx;
  __syncthreads();
  if (tid == 0) sred = fmaxf(fmaxf(wred[0], wred[1]), fmaxf(wred[2], wred[3]));
  __syncthreads();
  mx = sred;
  __syncthreads();
  float e[8];
  float sum = 0.f;
  #pragma unroll
  for (int i = 0; i < 8; ++i) { e[i] = __expf(a[i] - mx); sum += e[i]; }
  #pragma unroll
  for (int off = 32; off >= 1; off >>= 1) sum += __shfl_xor(sum, off);
  if (lane == 0) wred[w] = sum;
  __syncthreads();
  if (tid == 0) sred = 1.0f / (wred[0] + wred[1] + wred[2] + wred[3]);
  __syncthreads();
  float inv = sred;
  #pragma unroll
  for (int i = 0; i < 8; ++i) out[(size_t)b * S_ + i * 256 + tid] = e[i] * inv;
}

extern "C" void kernel_launch(void* const* d_in, const int* in_sizes, int n_in,
                              void* d_out, int out_size, void* d_ws, size_t ws_size,
                              hipStream_t stream) {
  (void)in_sizes; (void)n_in; (void)out_size;
  if (ws_size < WS_NEED) return;
  const float* sEmb = (const float*)d_in[0];
  const float* dEmb = (const float*)d_in[1];
  const float* dec  = (const float*)d_in[2];
  const unsigned char* mask = (const unsigned char*)d_in[3];
  const float* v    = (const float*)d_in[4];
  const float* W    = (const float*)d_in[5];
  const float* v2   = (const float*)d_in[6];
  const float* W2   = (const float*)d_in[7];

  char* ws = (char*)d_ws;
  unsigned short* wsA = (unsigned short*)(ws);
  int*   flag  = (int*)  (ws + 114688);
  float* c1    = (float*)(ws + 131072);
  float* c2    = (float*)(ws + 262144);
  float* ctx   = (float*)(ws + 393216);
  float* attns = (float*)(ws + 524288);
  float* score = (float*)(ws + 2621440);
  bool useT = (ws_size >= WS_T_NEED);
  unsigned short* wsT = useT ? (unsigned short*)(ws + WST_OFF) : nullptr;

  prep_wfrags<<<192, 256, 0, stream>>>(W, W2, wsA);
  prep_c1<<<B_, 128, 0, stream>>>(W, dec, c1);
  detect_mask<<<1, 256, 0, stream>>>(mask, flag);
  stage1<<<dim3(4, B_), 256, 0, stream>>>(sEmb, dEmb, wsA, c1, v, attns, wsT);
  if (useT) {
    fuse2<<<B_, 512, 0, stream>>>(attns, wsT, wsA, W2, v2, mask, flag, (float*)d_out);
  } else {
    kmid_a<<<dim3(4, B_), 256, 0, stream>>>(attns, sEmb, ctx);
    kmid_b<<<B_, 128, 0, stream>>>(W2, ctx, c2);
    stage2F<<<dim3(32, B_), 256, 0, stream>>>(sEmb, wsA, c2, v2, mask, flag, score);
    ksoftmax<<<B_, 256, 0, stream>>>(score, (float*)d_out);
  }
}